// Round 7
// baseline (522.440 us; speedup 1.0000x reference)
//
#include <hip/hip_runtime.h>

constexpr int BB   = 128;   // batch
constexpr int NSUP = 25;    // support samples
constexpr int NWAY = 5;
constexpr int NTOT = 125;   // NSUP*NWAY
constexpr int NQ   = 75;
constexpr int DIM  = 2560;
constexpr int MAXIT = 15;

#define FMA4(acc, zz, v)                     \
  acc.x = fmaf(zz, v.x, acc.x);              \
  acc.y = fmaf(zz, v.y, acc.y);              \
  acc.z = fmaf(zz, v.z, acc.z);              \
  acc.w = fmaf(zz, v.w, acc.w)

#define DOT4(a, u, vv) a += u.x*vv.x + u.y*vv.y + u.z*vv.z + u.w*vv.w

// ---------------------------------------------------------------------------
// helpers
// ---------------------------------------------------------------------------
__device__ __forceinline__ float frcp(float x) {
#if __has_builtin(__builtin_amdgcn_rcpf)
  return __builtin_amdgcn_rcpf(x);   // v_rcp_f32, ~1 ulp — fine inside IPM
#else
  return 1.0f / x;
#endif
}

// broadcast lane sl (compile-time const after unroll) -> SGPR, feeds v_fma
__device__ __forceinline__ float rlane(float v, int sl) {
  return __uint_as_float(__builtin_amdgcn_readlane(__float_as_uint(v), (unsigned)sl));
}

__device__ __forceinline__ float bfly_sum(float v) {
#pragma unroll
  for (int m = 32; m; m >>= 1) v += __shfl_xor(v, m);
  return v;
}
__device__ __forceinline__ float bfly_min(float v) {
#pragma unroll
  for (int m = 32; m; m >>= 1) v = fminf(v, __shfl_xor(v, m));
  return v;
}

// In-place Gauss-Jordan inverse of symmetric 25x25, column-per-lane (lane j
// holds column j in R[0..24]; one matrix per WAVE). Broadcasts are single
// v_readlane -> SGPR consumed directly by v_fma: pure VALU, no LDS waits.
// Lanes j>=25 compute garbage that is never sourced (readlane only reads
// lanes 0..24; reductions are act-guarded).
template <int K>
__device__ __forceinline__ void gj_step_rl(float (&R)[25], int j) {
  float pinv = frcp(rlane(R[K], K));
  bool  piv  = (j == K);
  float ph   = piv ? pinv : R[K] * pinv;
#pragma unroll
  for (int i = 0; i < 25; ++i) {
    if (i == K) continue;
    float f    = rlane(R[i], K);
    float base = piv ? 0.0f : R[i];
    R[i] = fmaf(-f, ph, base);
  }
  R[K] = ph;
}

template <int K>
__device__ __forceinline__ void gj25_rec(float (&R)[25], int j) {
  gj_step_rl<K>(R, j);
  if constexpr (K + 1 < 25) gj25_rec<K + 1>(R, j);
}
__device__ __forceinline__ void gj25(float (&R)[25], int j) {
  gj25_rec<0>(R, j);
}

// y[lane j] = sum_m row[m] * x[lane m]  (row held in this lane's registers)
__device__ __forceinline__ float mv25rl(const float (&row)[25], float x) {
  float a0 = 0.f, a1 = 0.f, a2 = 0.f, a3 = 0.f, a4 = 0.f;
#pragma unroll
  for (int m = 0; m < 5; ++m) {
    a0 = fmaf(row[m],      rlane(x, m),      a0);
    a1 = fmaf(row[5 + m],  rlane(x, 5 + m),  a1);
    a2 = fmaf(row[10 + m], rlane(x, 10 + m), a2);
    a3 = fmaf(row[15 + m], rlane(x, 15 + m), a3);
    a4 = fmaf(row[20 + m], rlane(x, 20 + m), a4);
  }
  return ((a0 + a1) + (a2 + a3)) + a4;
}

// ---------------------------------------------------------------------------
// Kernel A: K[b] = support[b] @ support[b]^T, split over 2 d-halves.
// ---------------------------------------------------------------------------
__global__ __launch_bounds__(256) void k_gram(const float* __restrict__ sup,
                                              float* __restrict__ Kpart) {
  const int b    = blockIdx.x;
  const int half = blockIdx.y;
  const int tid  = threadIdx.x;
  const int wv   = tid >> 6;
  const int ln   = tid & 63;

  __shared__ float tile[28][260];
  __shared__ float accb[4][49][16];

  for (int c = tid; c < 3 * 260; c += 256) tile[25 + c / 260][c % 260] = 0.0f;

  const float* S = sup + (size_t)b * NSUP * DIM + half * 1280;

  float acc[4][4];
#pragma unroll
  for (int x = 0; x < 4; ++x)
#pragma unroll
    for (int y = 0; y < 4; ++y) acc[x][y] = 0.0f;

  const int ti = ln / 7, tj = ln % 7;
  const int i0 = 4 * ti, j0 = 4 * tj;

  for (int ch = 0; ch < 5; ++ch) {
    __syncthreads();
    for (int q = tid; q < 1600; q += 256) {
      int rr = q >> 6, c4 = q & 63;
      float4 v = *(const float4*)(S + rr * DIM + ch * 256 + 4 * c4);
      *(float4*)&tile[rr][4 * c4] = v;
    }
    __syncthreads();
    if (ln < 49) {
#pragma unroll
      for (int c = 0; c < 16; ++c) {
        const int d4 = (wv * 16 + c) * 4;
        float4 av[4], bv[4];
#pragma unroll
        for (int x = 0; x < 4; ++x) av[x] = *(const float4*)&tile[i0 + x][d4];
#pragma unroll
        for (int y = 0; y < 4; ++y) bv[y] = *(const float4*)&tile[j0 + y][d4];
#pragma unroll
        for (int x = 0; x < 4; ++x)
#pragma unroll
          for (int y = 0; y < 4; ++y) {
            acc[x][y] += av[x].x * bv[y].x + av[x].y * bv[y].y +
                         av[x].z * bv[y].z + av[x].w * bv[y].w;
          }
      }
    }
  }

  if (ln < 49) {
#pragma unroll
    for (int x = 0; x < 4; ++x)
#pragma unroll
      for (int y = 0; y < 4; ++y) accb[wv][ln][x * 4 + y] = acc[x][y];
  }
  __syncthreads();

  for (int p = tid; p < 625; p += 256) {
    int i = p / 25, jx = p % 25;
    int lx = (i / 4) * 7 + (jx / 4);
    int sx = (i % 4) * 4 + (jx % 4);
    float v = accb[0][lx][sx] + accb[1][lx][sx] + accb[2][lx][sx] + accb[3][lx][sx];
    Kpart[((size_t)half * BB + b) * 625 + p] = v;
  }
}

// ---------------------------------------------------------------------------
// Kernel B: Mehrotra IPM, one block (320 threads = 5 waves) per batch element.
// Wave w owns way-matrix H_w, column-per-lane, readlane broadcasts (pure
// VALU). Symmetry: post-GJ register column == needed row, so no LDS
// transpose for W or S^-1; S^-1 computed redundantly per wave; nu kept in
// registers (identical across waves). 6 barriers/iteration.
// ---------------------------------------------------------------------------
__global__ __launch_bounds__(320, 1) void qp_solve5(const float* __restrict__ Kpart,
                                                    const int* __restrict__ labels,
                                                    float* __restrict__ zout) {
  const int b   = blockIdx.x;
  const int tid = threadIdx.x;
  const int w   = tid >> 6;          // wave = way 0..4
  const int j   = tid & 63;          // lane
  const bool act = (j < 25);
  const int jc  = act ? j : 0;

  __shared__ float Klds[25][26];
  __shared__ float WT[5][25][27];    // W_w row jc (stride 27: conflict-free)
  __shared__ float Zl[5][28];
  __shared__ float Vb[5][28];
  __shared__ float MU[8], AA[8], PP[8], CC[8];

  for (int p = tid; p < 625; p += 320)
    Klds[p / 25][p % 25] =
        Kpart[(size_t)b * 625 + p] + Kpart[(size_t)(BB + b) * 625 + p];

  int lab = labels[b * 25 + jc];
  float oh = (lab == w) ? 1.0f : 0.0f;
  float e_ = -oh;
  float z_ = 0.1f * oh - 1.0f;   // h - 1
  float s_ = 1.0f, lm_ = 1.0f, nu_ = 0.0f;

  if (act) Zl[w][jc] = z_;
  {
    float sl = act ? s_ * lm_ : 0.0f;
    sl = bfly_sum(sl);
    if (j == 0) MU[w] = sl;
  }
  __syncthreads();

  float Kc[25];   // K row jc == column jc (symmetric)
#pragma unroll
  for (int i = 0; i < 25; ++i) Kc[i] = Klds[jc][i];

  float R[25], Sr[25];

#pragma unroll 1
  for (int it = 0; it < MAXIT; ++it) {
    // ---- residuals ----
    float mu = (MU[0] + MU[1] + MU[2] + MU[3] + MU[4]) * (1.0f / 125.0f);
    float rp = Zl[0][jc] + Zl[1][jc] + Zl[2][jc] + Zl[3][jc] + Zl[4][jc];
    float d_ = lm_ / s_;
    float kz = mv25rl(Kc, z_);
    float rd = kz + z_ + e_ + lm_ + nu_;
    float rhs1 = lm_ - rd;                   // -r_d + lam

    // ---- H = K + I + diag(lam/s); invert in registers (pure VALU GJ) ----
#pragma unroll
    for (int i = 0; i < 25; ++i) R[i] = Kc[i] + ((j == i) ? (1.0f + d_) : 0.0f);
    gj25(R, j);
    // R = column jc of W_w = row jc (W symmetric)
    float v1 = mv25rl(R, rhs1);
    if (act) {
      Vb[w][jc] = v1;
#pragma unroll
      for (int i = 0; i < 25; ++i) WT[w][jc][i] = R[i];
    }
    __syncthreads();                          // B_A: W + Vb published

    // ---- S = sum_w W_w (row jc), invert redundantly per wave ----
#pragma unroll
    for (int i = 0; i < 25; ++i)
      Sr[i] = WT[0][jc][i] + WT[1][jc][i] + WT[2][jc][i] +
              WT[3][jc][i] + WT[4][jc][i];
    gj25(Sr, j);                              // Sr = S^{-1} row jc (symmetric)

    // ---- predictor ----
    float u = Vb[0][jc] + Vb[1][jc] + Vb[2][jc] + Vb[3][jc] + Vb[4][jc];
    float t = u + rp;
    float dn1 = mv25rl(Sr, t);
    float r2 = rhs1 - dn1;
    float dz1 = mv25rl(R, r2);
    float ds1 = -dz1;
    float dl1 = fmaf(d_, dz1, -lm_);
    float cand = 1.0f;
    if (act) {
      if (ds1 < 0.0f) cand = fminf(cand, -s_ / ds1);
      if (dl1 < 0.0f) cand = fminf(cand, -lm_ / dl1);
    }
    cand = bfly_min(cand);
    if (j == 0) AA[w] = cand;
    __syncthreads();                          // B_C
    float a_aff = fminf(fminf(fminf(AA[0], AA[1]), fminf(AA[2], AA[3])), AA[4]);
    float pr = act ? (s_ + a_aff * ds1) * (lm_ + a_aff * dl1) : 0.0f;
    pr = bfly_sum(pr);
    if (j == 0) PP[w] = pr;
    __syncthreads();                          // B_D
    float mu_aff = (PP[0] + PP[1] + PP[2] + PP[3] + PP[4]) * (1.0f / 125.0f);
    float rt = mu_aff / mu;
    float sg = rt * rt * rt * mu;

    // ---- corrector ----
    float rc = sg - ds1 * dl1;
    float rhsc = lm_ - rd - rc / s_;
    float v2 = mv25rl(R, rhsc);
    if (act) Vb[w][jc] = v2;
    __syncthreads();                          // B_E
    float u2 = Vb[0][jc] + Vb[1][jc] + Vb[2][jc] + Vb[3][jc] + Vb[4][jc];
    float t2 = u2 + rp;
    float dn2 = mv25rl(Sr, t2);
    float r2c = rhsc - dn2;
    float dz2 = mv25rl(R, r2c);
    float ds2 = -dz2;
    float dl2 = rc / s_ - lm_ + d_ * dz2;
    float c2 = 1.0f;
    if (act) {
      if (ds2 < 0.0f) c2 = fminf(c2, -s_ / ds2);
      if (dl2 < 0.0f) c2 = fminf(c2, -lm_ / dl2);
    }
    c2 = bfly_min(c2);
    if (j == 0) CC[w] = c2;
    __syncthreads();                          // B_F
    float a = 0.995f * fminf(fminf(fminf(CC[0], CC[1]), fminf(CC[2], CC[3])), CC[4]);

    // ---- update ----
    z_  = fmaf(a, dz2, z_);
    s_  = fmaf(a, ds2, s_);
    lm_ = fmaf(a, dl2, lm_);
    nu_ = fmaf(a, dn2, nu_);   // dn2 identical across waves for same lane
    if (act) Zl[w][jc] = z_;
    {
      float sl = act ? s_ * lm_ : 0.0f;
      sl = bfly_sum(sl);
      if (j == 0) MU[w] = sl;
    }
    __syncthreads();                          // B_G (= top of next iter)
  }

  if (act) zout[(size_t)b * NTOT + jc * 5 + w] = z_;
}

// ---------------------------------------------------------------------------
// Kernel C1: ws[b][w][d] = sum_s z[s,w] * support[s][d]
// ---------------------------------------------------------------------------
__global__ __launch_bounds__(256) void k_ws(const float* __restrict__ sup,
                                            const float* __restrict__ zsol,
                                            float* __restrict__ ws) {
  const int b   = blockIdx.x;
  const int tid = threadIdx.x;
  __shared__ float zsh[NTOT];
  if (tid < NTOT) zsh[tid] = zsol[(size_t)b * NTOT + tid];
  __syncthreads();

  const float* Sb = sup + (size_t)b * NSUP * DIM;
  for (int d4 = tid; d4 < 640; d4 += 256) {
    float4 a0 = {0,0,0,0}, a1 = {0,0,0,0}, a2 = {0,0,0,0}, a3 = {0,0,0,0}, a4 = {0,0,0,0};
#pragma unroll
    for (int s = 0; s < 25; ++s) {
      float4 v = *(const float4*)(Sb + s * DIM + 4 * d4);
      float z0 = zsh[s*5+0], z1 = zsh[s*5+1], z2 = zsh[s*5+2], z3 = zsh[s*5+3], z4 = zsh[s*5+4];
      FMA4(a0, z0, v); FMA4(a1, z1, v); FMA4(a2, z2, v); FMA4(a3, z3, v); FMA4(a4, z4, v);
    }
    float* W = ws + (size_t)b * NWAY * DIM;
    *(float4*)(W + 0*DIM + 4*d4) = a0;
    *(float4*)(W + 1*DIM + 4*d4) = a1;
    *(float4*)(W + 2*DIM + 4*d4) = a2;
    *(float4*)(W + 3*DIM + 4*d4) = a3;
    *(float4*)(W + 4*DIM + 4*d4) = a4;
  }
}

// ---------------------------------------------------------------------------
// Kernel C2: logits[b][q][w] = scale * dot(query[b][q], ws[b][w])
// ---------------------------------------------------------------------------
__global__ __launch_bounds__(256) void k_logits2(const float* __restrict__ query,
                                                 const float* __restrict__ scale,
                                                 const float* __restrict__ ws,
                                                 float* __restrict__ out) {
  const int b   = blockIdx.x;
  const int qt  = blockIdx.y;
  const int tid = threadIdx.x;
  const int wv  = tid >> 6, ln = tid & 63;

  __shared__ float wsb[5][2564];
  for (int p = tid; p < 3200; p += 256) {
    int w = p / 640, c = p % 640;
    *(float4*)&wsb[w][4 * c] = *(const float4*)(ws + ((size_t)b * NWAY + w) * DIM + 4 * c);
  }
  __syncthreads();

  const float sc = scale[0];
  const int q0 = qt * 15, q1 = q0 + 15;
  for (int q = q0 + wv; q < q1; q += 4) {
    const float* Q = query + ((size_t)b * NQ + q) * DIM;
    float a0 = 0.f, a1 = 0.f, a2 = 0.f, a3 = 0.f, a4 = 0.f;
#pragma unroll
    for (int c = 0; c < 10; ++c) {
      int d4 = (c * 64 + ln) * 4;
      float4 qv = *(const float4*)(Q + d4);
      float4 w0 = *(const float4*)&wsb[0][d4];
      float4 w1 = *(const float4*)&wsb[1][d4];
      float4 w2 = *(const float4*)&wsb[2][d4];
      float4 w3 = *(const float4*)&wsb[3][d4];
      float4 w4 = *(const float4*)&wsb[4][d4];
      DOT4(a0, qv, w0); DOT4(a1, qv, w1); DOT4(a2, qv, w2); DOT4(a3, qv, w3); DOT4(a4, qv, w4);
    }
#pragma unroll
    for (int off = 32; off; off >>= 1) {
      a0 += __shfl_xor(a0, off); a1 += __shfl_xor(a1, off); a2 += __shfl_xor(a2, off);
      a3 += __shfl_xor(a3, off); a4 += __shfl_xor(a4, off);
    }
    if (ln == 0) {
      float* O = out + ((size_t)b * NQ + q) * NWAY;
      O[0] = sc*a0; O[1] = sc*a1; O[2] = sc*a2; O[3] = sc*a3; O[4] = sc*a4;
    }
  }
}

// ---------------------------------------------------------------------------
// Fallback fused logits (if workspace too small for ws buffer)
// ---------------------------------------------------------------------------
__global__ __launch_bounds__(256) void k_logits(const float* __restrict__ sup,
                                                const float* __restrict__ query,
                                                const float* __restrict__ scale,
                                                const float* __restrict__ zsol,
                                                float* __restrict__ out) {
  const int b   = blockIdx.x;
  const int hq  = blockIdx.y;
  const int tid = threadIdx.x;

  __shared__ float wsb[5][2564];
  __shared__ float zsh[128];

  if (tid < NTOT) zsh[tid] = zsol[(size_t)b * NTOT + tid];
  __syncthreads();

  const float* Sb = sup + (size_t)b * NSUP * DIM;
  for (int d4 = tid; d4 < 640; d4 += 256) {
    float4 a0 = {0,0,0,0}, a1 = {0,0,0,0}, a2 = {0,0,0,0}, a3 = {0,0,0,0}, a4 = {0,0,0,0};
#pragma unroll
    for (int s = 0; s < 25; ++s) {
      float4 v = *(const float4*)(Sb + s * DIM + 4 * d4);
      float z0 = zsh[s*5+0], z1 = zsh[s*5+1], z2 = zsh[s*5+2], z3 = zsh[s*5+3], z4 = zsh[s*5+4];
      FMA4(a0, z0, v); FMA4(a1, z1, v); FMA4(a2, z2, v); FMA4(a3, z3, v); FMA4(a4, z4, v);
    }
    *(float4*)&wsb[0][4*d4] = a0; *(float4*)&wsb[1][4*d4] = a1; *(float4*)&wsb[2][4*d4] = a2;
    *(float4*)&wsb[3][4*d4] = a3; *(float4*)&wsb[4][4*d4] = a4;
  }
  __syncthreads();

  const float sc = scale[0];
  const int wv = tid >> 6, ln = tid & 63;
  const int q0 = hq * 38;
  const int q1 = (hq == 0) ? 38 : 75;

  for (int q = q0 + wv; q < q1; q += 4) {
    const float* Q = query + ((size_t)b * NQ + q) * DIM;
    float a0 = 0.f, a1 = 0.f, a2 = 0.f, a3 = 0.f, a4 = 0.f;
#pragma unroll
    for (int c = 0; c < 10; ++c) {
      int d4 = (c * 64 + ln) * 4;
      float4 qv = *(const float4*)(Q + d4);
      float4 w0 = *(const float4*)&wsb[0][d4];
      float4 w1 = *(const float4*)&wsb[1][d4];
      float4 w2 = *(const float4*)&wsb[2][d4];
      float4 w3 = *(const float4*)&wsb[3][d4];
      float4 w4 = *(const float4*)&wsb[4][d4];
      DOT4(a0, qv, w0); DOT4(a1, qv, w1); DOT4(a2, qv, w2); DOT4(a3, qv, w3); DOT4(a4, qv, w4);
    }
#pragma unroll
    for (int off = 32; off; off >>= 1) {
      a0 += __shfl_xor(a0, off); a1 += __shfl_xor(a1, off); a2 += __shfl_xor(a2, off);
      a3 += __shfl_xor(a3, off); a4 += __shfl_xor(a4, off);
    }
    if (ln == 0) {
      float* O = out + ((size_t)b * NQ + q) * NWAY;
      O[0] = sc*a0; O[1] = sc*a1; O[2] = sc*a2; O[3] = sc*a3; O[4] = sc*a4;
    }
  }
}

// ---------------------------------------------------------------------------
extern "C" void kernel_launch(void* const* d_in, const int* in_sizes, int n_in,
                              void* d_out, int out_size, void* d_ws, size_t ws_size,
                              hipStream_t stream) {
  (void)in_sizes; (void)n_in; (void)out_size;
  const float* query   = (const float*)d_in[0];
  const float* support = (const float*)d_in[1];
  const float* scale   = (const float*)d_in[2];
  const int*   labels  = (const int*)d_in[3];
  float* out = (float*)d_out;

  float* Kpart = (float*)d_ws;                       // [2][B][625]
  float* zsol  = Kpart + 2 * BB * 625;               // [B][125]
  float* wsbuf = zsol + BB * NTOT;                   // [B][5][2560]
  const size_t need = (size_t)(2*BB*625 + BB*NTOT + BB*NWAY*DIM) * 4;

  dim3 gA(BB, 2);
  k_gram<<<gA, 256, 0, stream>>>(support, Kpart);

  qp_solve5<<<dim3(BB), 320, 0, stream>>>(Kpart, labels, zsol);

  if (ws_size >= need) {
    k_ws<<<dim3(BB), 256, 0, stream>>>(support, zsol, wsbuf);
    k_logits2<<<dim3(BB, 5), 256, 0, stream>>>(query, scale, wsbuf, out);
  } else {
    k_logits<<<dim3(BB, 2), 256, 0, stream>>>(support, query, scale, zsol, out);
  }
}